// Round 4
// baseline (586.357 us; speedup 1.0000x reference)
//
#include <hip/hip_runtime.h>
#include <cmath>

#define NB   1024   // batches
#define NN   1024   // rows
#define MM   64     // cols
#define NT   512    // threads per block
#define NW   (NT / 64)
#define ITS  (NN / 32)   // 32 row-iterations; each covers rows rg, rg+32x
#define GRID 256         // persistent blocks: one per CU
#define BPB  (NB / GRID) // 4 batches per block

typedef float f32x4 __attribute__((ext_vector_type(4)));

// Block-wide sum over NT threads (NW waves). Trailing barrier protects s_tmp reuse.
__device__ __forceinline__ float block_sum(float v, float* s_tmp) {
    #pragma unroll
    for (int off = 32; off > 0; off >>= 1) v += __shfl_xor(v, off, 64);
    if ((threadIdx.x & 63) == 0) s_tmp[threadIdx.x >> 6] = v;
    __syncthreads();
    float r = 0.0f;
    #pragma unroll
    for (int i = 0; i < NW; ++i) r += s_tmp[i];
    __syncthreads();
    return r;
}

__device__ __forceinline__ float block_max(float v, float* s_tmp) {
    #pragma unroll
    for (int off = 32; off > 0; off >>= 1) v = fmaxf(v, __shfl_xor(v, off, 64));
    if ((threadIdx.x & 63) == 0) s_tmp[threadIdx.x >> 6] = v;
    __syncthreads();
    float r = s_tmp[0];
    #pragma unroll
    for (int i = 1; i < NW; ++i) r = fmaxf(r, s_tmp[i]);
    __syncthreads();
    return r;
}

__global__ void __launch_bounds__(NT, 2) ntm_fused(
    const float* __restrict__ memory,
    const float* __restrict__ k,
    const float* __restrict__ beta,
    const float* __restrict__ g,
    const float* __restrict__ s,
    const float* __restrict__ gamma,
    const float* __restrict__ w_prev,
    const float* __restrict__ e,
    const float* __restrict__ a,
    float* __restrict__ out)
{
    __shared__ float  s_sc[NN];     // scores, then interpolated wg
    __shared__ float  s_w[NN];      // final sharpened+normalized weights
    __shared__ float  s_k[MM];
    __shared__ float  s_tmp[NW];
    __shared__ f32x4  s_red[NW * 16];

    const int t    = threadIdx.x;
    const int cg   = t & 15;   // column group: cols [4*cg, 4*cg+3]
    const int rg   = t >> 4;   // row subgroup: 0..31
    const int wid  = t >> 6;
    const int lane = t & 63;
    const int coff = 4 * cg;

    f32x4 mc[ITS];              // register cache: this thread's 512B of the slice
    const int bbase = blockIdx.x * BPB;

    // prologue: issue all loads for the first batch (max MLP)
    {
        const float* memb = memory + (size_t)bbase * NN * MM;
        #pragma unroll
        for (int it = 0; it < ITS; ++it)
            mc[it] = __builtin_nontemporal_load(
                (const f32x4*)(memb + (size_t)(it * 32 + rg) * MM + coff));
    }

    for (int bi = 0; bi < BPB; ++bi) {
        const int  b  = bbase + bi;
        const bool pf = (bi + 1 < BPB);
        const float* membn = memory + (size_t)(b + 1) * NN * MM;  // used only if pf
        float*       outb  = out    + (size_t)b * (NN + 1) * MM;

        // per-batch small operands
        const float bet = beta[b], gb = g[b];
        const float s0 = s[b * 3 + 0], s1 = s[b * 3 + 1], s2 = s[b * 3 + 2];
        const float gam = gamma[b];
        const float wp0 = w_prev[(size_t)b * NN + t];
        const float wp1 = w_prev[(size_t)b * NN + t + 512];
        const f32x4 e4 = *(const f32x4*)(e + b * MM + coff);
        const f32x4 a4 = *(const f32x4*)(a + b * MM + coff);

        // --- k staging + ||k_e|| (block_sum's barrier orders s_k) ---
        if (t < MM) s_k[t] = k[b * MM + t] + 1e-16f;
        float kq = (t < MM) ? s_k[t] * s_k[t] : 0.0f;
        float kden = fmaxf(sqrtf(block_sum(kq, s_tmp)), 1e-8f);
        const f32x4 k4 = ((const f32x4*)s_k)[cg];

        // --- pass 1: cosine-sim scores from the register cache ---
        #pragma unroll
        for (int it = 0; it < ITS; ++it) {
            int n = it * 32 + rg;
            f32x4 m4 = mc[it];
            float ex = m4.x + 1e-16f, ey = m4.y + 1e-16f;
            float ez = m4.z + 1e-16f, ew = m4.w + 1e-16f;
            float d = ex * k4.x + ey * k4.y + ez * k4.z + ew * k4.w;
            float q = ex * ex + ey * ey + ez * ez + ew * ew;
            #pragma unroll
            for (int off = 8; off > 0; off >>= 1) {
                d += __shfl_xor(d, off, 64);
                q += __shfl_xor(q, off, 64);
            }
            if (cg == 0) s_sc[n] = bet * d / (fmaxf(sqrtf(q), 1e-8f) * kden);
        }
        __syncthreads();

        // --- softmax over N (each thread owns indices t, t+512) ---
        float sc0 = s_sc[t], sc1 = s_sc[t + 512];
        float mx = block_max(fmaxf(sc0, sc1), s_tmp);
        float e0 = __expf(sc0 - mx), e1 = __expf(sc1 - mx);
        float inv = 1.0f / block_sum(e0 + e1, s_tmp);

        // --- interpolate ---
        const float omg = 1.0f - gb;
        s_sc[t]       = gb * e0 * inv + omg * wp0;
        s_sc[t + 512] = gb * e1 * inv + omg * wp1;
        __syncthreads();

        // --- shift (3-tap circular) + sharpen ---
        float wv0, wv1;
        {
            int nm = (t == 0) ? NN - 1 : t - 1;
            wv0 = powf(s0 * s_sc[nm] + s1 * s_sc[t] + s2 * s_sc[t + 1], gam);
        }
        {
            int n = t + 512;
            int np = (n == NN - 1) ? 0 : n + 1;
            wv1 = powf(s0 * s_sc[n - 1] + s1 * s_sc[n] + s2 * s_sc[np], gam);
        }
        float winv = 1.0f / (block_sum(wv0 + wv1, s_tmp) + 1e-16f);
        s_w[t]       = wv0 * winv;
        s_w[t + 512] = wv1 * winv;
        __syncthreads();

        // --- pass 2: update from registers; stores interleaved 1:1 with
        //     next-batch prefetch loads (in-order vmem retire => consuming
        //     mc[0] next iteration waits only on the first store/load pair) ---
        f32x4 acc = {0.f, 0.f, 0.f, 0.f};
        #pragma unroll
        for (int it = 0; it < ITS; ++it) {
            int n = it * 32 + rg;
            f32x4 m4 = mc[it];
            float wn = s_w[n];
            acc.x += wn * m4.x; acc.y += wn * m4.y;
            acc.z += wn * m4.z; acc.w += wn * m4.w;
            f32x4 o;
            o.x = m4.x * (1.0f - wn * e4.x) + wn * a4.x;
            o.y = m4.y * (1.0f - wn * e4.y) + wn * a4.y;
            o.z = m4.z * (1.0f - wn * e4.z) + wn * a4.z;
            o.w = m4.w * (1.0f - wn * e4.w) + wn * a4.w;
            __builtin_nontemporal_store(o, (f32x4*)(outb + (size_t)(n + 1) * MM + coff));
            if (pf)
                mc[it] = __builtin_nontemporal_load(
                    (const f32x4*)(membn + (size_t)n * MM + coff));
        }

        // --- reduce read accumulator; row 0 of outb = read ---
        #pragma unroll
        for (int off = 16; off <= 32; off <<= 1) {
            acc.x += __shfl_xor(acc.x, off, 64);
            acc.y += __shfl_xor(acc.y, off, 64);
            acc.z += __shfl_xor(acc.z, off, 64);
            acc.w += __shfl_xor(acc.w, off, 64);
        }
        if (lane < 16) s_red[wid * 16 + lane] = acc;
        __syncthreads();
        if (t < 16) {
            f32x4 r = {0.f, 0.f, 0.f, 0.f};
            #pragma unroll
            for (int wv = 0; wv < NW; ++wv) {
                f32x4 v = s_red[wv * 16 + t];
                r.x += v.x; r.y += v.y; r.z += v.z; r.w += v.w;
            }
            __builtin_nontemporal_store(r, (f32x4*)(outb + 4 * t));
        }
        __syncthreads();   // protect s_red / order shared reuse for next batch
    }
}

extern "C" void kernel_launch(void* const* d_in, const int* in_sizes, int n_in,
                              void* d_out, int out_size, void* d_ws, size_t ws_size,
                              hipStream_t stream) {
    ntm_fused<<<GRID, NT, 0, stream>>>(
        (const float*)d_in[0],  // memory (B,N,M)
        (const float*)d_in[1],  // k      (B,M)
        (const float*)d_in[2],  // beta   (B,1)
        (const float*)d_in[3],  // g      (B,1)
        (const float*)d_in[4],  // s      (B,3)
        (const float*)d_in[5],  // gamma  (B,1)
        (const float*)d_in[6],  // w_prev (B,N)
        (const float*)d_in[7],  // e      (B,M)
        (const float*)d_in[8],  // a      (B,M)
        (float*)d_out);
}

// Round 5
// 498.088 us; speedup vs baseline: 1.1772x; 1.1772x over previous
//
#include <hip/hip_runtime.h>
#include <cmath>

#define NB   1024   // batches
#define NN   1024   // rows
#define MM   64     // cols
#define NT   512    // threads per block
#define NW   (NT / 64)
#define ITS  (NN / 32)   // 32 row-iterations; thread covers rows rg+32*it
#define GRID 256         // persistent blocks: one per CU
#define BPB  (NB / GRID) // 4 batches per block

typedef float f32x4 __attribute__((ext_vector_type(4)));

// Block-wide sum over NT threads (NW waves). Trailing barrier protects s_tmp reuse.
__device__ __forceinline__ float block_sum(float v, float* s_tmp) {
    #pragma unroll
    for (int off = 32; off > 0; off >>= 1) v += __shfl_xor(v, off, 64);
    if ((threadIdx.x & 63) == 0) s_tmp[threadIdx.x >> 6] = v;
    __syncthreads();
    float r = 0.0f;
    #pragma unroll
    for (int i = 0; i < NW; ++i) r += s_tmp[i];
    __syncthreads();
    return r;
}

__device__ __forceinline__ float block_max(float v, float* s_tmp) {
    #pragma unroll
    for (int off = 32; off > 0; off >>= 1) v = fmaxf(v, __shfl_xor(v, off, 64));
    if ((threadIdx.x & 63) == 0) s_tmp[threadIdx.x >> 6] = v;
    __syncthreads();
    float r = s_tmp[0];
    #pragma unroll
    for (int i = 1; i < NW; ++i) r = fmaxf(r, s_tmp[i]);
    __syncthreads();
    return r;
}

// Process one batch from the register cache mc. If PF, pass 2 interleaves
// 1:1 prefetch loads of batch b+1 into mc (unconditional writes -> SROA-safe).
template<bool PF>
__device__ __forceinline__ void process_batch(
    int b,
    f32x4 (&mc)[ITS],
    const float* __restrict__ memory,
    const float* __restrict__ k,
    const float* __restrict__ beta,
    const float* __restrict__ g,
    const float* __restrict__ s,
    const float* __restrict__ gamma,
    const float* __restrict__ w_prev,
    const float* __restrict__ e,
    const float* __restrict__ a,
    float* __restrict__ out,
    float* s_sc, float* s_w, float* s_k, float* s_tmp, f32x4* s_red)
{
    const int t    = threadIdx.x;
    const int cg   = t & 15;
    const int rg   = t >> 4;
    const int wid  = t >> 6;
    const int lane = t & 63;
    const int coff = 4 * cg;

    const float* membn = memory + (size_t)(b + 1) * NN * MM;  // used only if PF
    float*       outb  = out    + (size_t)b * (NN + 1) * MM;

    // per-batch small operands
    const float bet = beta[b], gb = g[b];
    const float s0 = s[b * 3 + 0], s1 = s[b * 3 + 1], s2 = s[b * 3 + 2];
    const float gam = gamma[b];
    const float wp0 = w_prev[(size_t)b * NN + t];
    const float wp1 = w_prev[(size_t)b * NN + t + 512];
    const f32x4 e4 = *(const f32x4*)(e + b * MM + coff);
    const f32x4 a4 = *(const f32x4*)(a + b * MM + coff);

    // --- k staging + ||k_e|| (block_sum's barrier orders s_k) ---
    if (t < MM) s_k[t] = k[b * MM + t] + 1e-16f;
    float kq = (t < MM) ? s_k[t] * s_k[t] : 0.0f;
    float kden = fmaxf(sqrtf(block_sum(kq, s_tmp)), 1e-8f);
    const f32x4 k4 = ((const f32x4*)s_k)[cg];

    // --- pass 1: cosine-sim scores from the register cache ---
    #pragma unroll
    for (int it = 0; it < ITS; ++it) {
        int n = it * 32 + rg;
        f32x4 m4 = mc[it];
        float ex = m4.x + 1e-16f, ey = m4.y + 1e-16f;
        float ez = m4.z + 1e-16f, ew = m4.w + 1e-16f;
        float d = ex * k4.x + ey * k4.y + ez * k4.z + ew * k4.w;
        float q = ex * ex + ey * ey + ez * ez + ew * ew;
        #pragma unroll
        for (int off = 8; off > 0; off >>= 1) {
            d += __shfl_xor(d, off, 64);
            q += __shfl_xor(q, off, 64);
        }
        if (cg == 0) s_sc[n] = bet * d / (fmaxf(sqrtf(q), 1e-8f) * kden);
    }
    __syncthreads();

    // --- softmax over N (each thread owns indices t, t+512) ---
    float sc0 = s_sc[t], sc1 = s_sc[t + 512];
    float mx = block_max(fmaxf(sc0, sc1), s_tmp);
    float e0 = __expf(sc0 - mx), e1 = __expf(sc1 - mx);
    float inv = 1.0f / block_sum(e0 + e1, s_tmp);

    // --- interpolate ---
    const float omg = 1.0f - gb;
    s_sc[t]       = gb * e0 * inv + omg * wp0;
    s_sc[t + 512] = gb * e1 * inv + omg * wp1;
    __syncthreads();

    // --- shift (3-tap circular) + sharpen ---
    float wv0, wv1;
    {
        int nm = (t == 0) ? NN - 1 : t - 1;
        wv0 = powf(s0 * s_sc[nm] + s1 * s_sc[t] + s2 * s_sc[t + 1], gam);
    }
    {
        int n = t + 512;
        int np = (n == NN - 1) ? 0 : n + 1;
        wv1 = powf(s0 * s_sc[n - 1] + s1 * s_sc[n] + s2 * s_sc[np], gam);
    }
    float winv = 1.0f / (block_sum(wv0 + wv1, s_tmp) + 1e-16f);
    s_w[t]       = wv0 * winv;
    s_w[t + 512] = wv1 * winv;
    __syncthreads();

    // --- pass 2: update from registers; stores interleaved 1:1 with
    //     next-batch prefetch loads (in-order vmem retire => pass 1 of the
    //     next batch consuming mc[0] waits only on the earliest pairs) ---
    f32x4 acc = {0.f, 0.f, 0.f, 0.f};
    #pragma unroll
    for (int it = 0; it < ITS; ++it) {
        int n = it * 32 + rg;
        f32x4 m4 = mc[it];
        float wn = s_w[n];
        acc.x += wn * m4.x; acc.y += wn * m4.y;
        acc.z += wn * m4.z; acc.w += wn * m4.w;
        f32x4 o;
        o.x = m4.x * (1.0f - wn * e4.x) + wn * a4.x;
        o.y = m4.y * (1.0f - wn * e4.y) + wn * a4.y;
        o.z = m4.z * (1.0f - wn * e4.z) + wn * a4.z;
        o.w = m4.w * (1.0f - wn * e4.w) + wn * a4.w;
        __builtin_nontemporal_store(o, (f32x4*)(outb + (size_t)(n + 1) * MM + coff));
        if constexpr (PF) {
            mc[it] = __builtin_nontemporal_load(
                (const f32x4*)(membn + (size_t)n * MM + coff));
        }
    }

    // --- reduce read accumulator; row 0 of outb = read ---
    #pragma unroll
    for (int off = 16; off <= 32; off <<= 1) {
        acc.x += __shfl_xor(acc.x, off, 64);
        acc.y += __shfl_xor(acc.y, off, 64);
        acc.z += __shfl_xor(acc.z, off, 64);
        acc.w += __shfl_xor(acc.w, off, 64);
    }
    if (lane < 16) s_red[wid * 16 + lane] = acc;
    __syncthreads();
    if (t < 16) {
        f32x4 r = {0.f, 0.f, 0.f, 0.f};
        #pragma unroll
        for (int wv = 0; wv < NW; ++wv) {
            f32x4 v = s_red[wv * 16 + t];
            r.x += v.x; r.y += v.y; r.z += v.z; r.w += v.w;
        }
        __builtin_nontemporal_store(r, (f32x4*)(outb + 4 * t));
    }
    __syncthreads();   // protect s_red reuse next batch
}

__global__ void __launch_bounds__(NT, 2) ntm_fused(
    const float* __restrict__ memory,
    const float* __restrict__ k,
    const float* __restrict__ beta,
    const float* __restrict__ g,
    const float* __restrict__ s,
    const float* __restrict__ gamma,
    const float* __restrict__ w_prev,
    const float* __restrict__ e,
    const float* __restrict__ a,
    float* __restrict__ out)
{
    __shared__ float  s_sc[NN];
    __shared__ float  s_w[NN];
    __shared__ float  s_k[MM];
    __shared__ float  s_tmp[NW];
    __shared__ f32x4  s_red[NW * 16];

    const int t    = threadIdx.x;
    const int cg   = t & 15;
    const int rg   = t >> 4;
    const int coff = 4 * cg;

    f32x4 mc[ITS];              // register cache: this thread's 512 B of the slice
    const int bbase = blockIdx.x * BPB;

    // prologue: issue all loads for the first batch (max MLP)
    {
        const float* memb = memory + (size_t)bbase * NN * MM;
        #pragma unroll
        for (int it = 0; it < ITS; ++it)
            mc[it] = __builtin_nontemporal_load(
                (const f32x4*)(memb + (size_t)(it * 32 + rg) * MM + coff));
    }

    // main: BPB-1 batches with cross-batch prefetch, then a peeled epilogue
    for (int bi = 0; bi < BPB - 1; ++bi)
        process_batch<true>(bbase + bi, mc, memory, k, beta, g, s, gamma,
                            w_prev, e, a, out, s_sc, s_w, s_k, s_tmp, s_red);
    process_batch<false>(bbase + BPB - 1, mc, memory, k, beta, g, s, gamma,
                         w_prev, e, a, out, s_sc, s_w, s_k, s_tmp, s_red);
}

extern "C" void kernel_launch(void* const* d_in, const int* in_sizes, int n_in,
                              void* d_out, int out_size, void* d_ws, size_t ws_size,
                              hipStream_t stream) {
    ntm_fused<<<GRID, NT, 0, stream>>>(
        (const float*)d_in[0],  // memory (B,N,M)
        (const float*)d_in[1],  // k      (B,M)
        (const float*)d_in[2],  // beta   (B,1)
        (const float*)d_in[3],  // g      (B,1)
        (const float*)d_in[4],  // s      (B,3)
        (const float*)d_in[5],  // gamma  (B,1)
        (const float*)d_in[6],  // w_prev (B,N)
        (const float*)d_in[7],  // e      (B,M)
        (const float*)d_in[8],  // a      (B,M)
        (float*)d_out);
}

// Round 6
// 470.799 us; speedup vs baseline: 1.2455x; 1.0580x over previous
//
#include <hip/hip_runtime.h>
#include <cmath>

#define NB   1024   // batches
#define NN   1024   // rows
#define MM   64     // cols
#define NT   512    // threads per block
#define NW   (NT / 64)
#define ITS  (NN / 32)   // thread covers rows rg+32*it
#define GRID 256         // persistent blocks: one per CU
#define BPB  (NB / GRID) // 4 batches per block

typedef float f32x4 __attribute__((ext_vector_type(4)));

// Raw barrier + LDS-producer drain ONLY. Unlike __syncthreads (which emits
// s_waitcnt vmcnt(0) and drains the global load/store burst), this leaves
// vmem ops in flight across the barrier -- the cross-batch prefetch and the
// store stream continue under the VALU middle section.
__device__ __forceinline__ void lds_barrier() {
    asm volatile("s_waitcnt lgkmcnt(0)\n\ts_barrier" ::: "memory");
}

__device__ __forceinline__ float block_sum(float v, float* s_tmp) {
    #pragma unroll
    for (int off = 32; off > 0; off >>= 1) v += __shfl_xor(v, off, 64);
    if ((threadIdx.x & 63) == 0) s_tmp[threadIdx.x >> 6] = v;
    lds_barrier();
    float r = 0.0f;
    #pragma unroll
    for (int i = 0; i < NW; ++i) r += s_tmp[i];
    lds_barrier();   // protect s_tmp reuse
    return r;
}

__device__ __forceinline__ float block_max(float v, float* s_tmp) {
    #pragma unroll
    for (int off = 32; off > 0; off >>= 1) v = fmaxf(v, __shfl_xor(v, off, 64));
    if ((threadIdx.x & 63) == 0) s_tmp[threadIdx.x >> 6] = v;
    lds_barrier();
    float r = s_tmp[0];
    #pragma unroll
    for (int i = 1; i < NW; ++i) r = fmaxf(r, s_tmp[i]);
    lds_barrier();
    return r;
}

// Per-batch small operands, kept in registers across the pipeline.
struct Ops {
    f32x4 k4, e4, a4;
    float kden, bet, gb, s0, s1, s2, gam, wp0, wp1;
};

// No LDS, no barriers: k-norm via in-wave shuffle reduce over the 16 column
// groups (lanes l..l+15 within each 16-lane group cover all 64 cols).
__device__ __forceinline__ Ops load_ops(
    int b, int coff,
    const float* __restrict__ k, const float* __restrict__ beta,
    const float* __restrict__ g, const float* __restrict__ s,
    const float* __restrict__ gamma, const float* __restrict__ w_prev,
    const float* __restrict__ e, const float* __restrict__ a)
{
    Ops o;
    const int t = threadIdx.x;
    f32x4 kv = *(const f32x4*)(k + b * MM + coff);
    o.k4.x = kv.x + 1e-16f; o.k4.y = kv.y + 1e-16f;
    o.k4.z = kv.z + 1e-16f; o.k4.w = kv.w + 1e-16f;
    float kq = o.k4.x * o.k4.x + o.k4.y * o.k4.y
             + o.k4.z * o.k4.z + o.k4.w * o.k4.w;
    #pragma unroll
    for (int off = 8; off > 0; off >>= 1) kq += __shfl_xor(kq, off, 64);
    o.kden = fmaxf(sqrtf(kq), 1e-8f);
    o.e4 = *(const f32x4*)(e + b * MM + coff);
    o.a4 = *(const f32x4*)(a + b * MM + coff);
    o.bet = beta[b]; o.gb = g[b];
    o.s0 = s[b * 3 + 0]; o.s1 = s[b * 3 + 1]; o.s2 = s[b * 3 + 2];
    o.gam = gamma[b];
    o.wp0 = w_prev[(size_t)b * NN + t];
    o.wp1 = w_prev[(size_t)b * NN + t + 512];
    return o;
}

// One batch from the register cache mc. If PF, pass 2 interleaves 1:1
// prefetch loads of batch b+1 into mc (unconditional writes -> SROA-safe),
// and batch b+1's small operands are loaded BEFORE the burst so consuming
// them next iteration doesn't drain it (in-order vmcnt).
template<bool PF>
__device__ __forceinline__ Ops process_batch(
    int b, f32x4 (&mc)[ITS], Ops op,
    const float* __restrict__ memory,
    const float* __restrict__ k,
    const float* __restrict__ beta,
    const float* __restrict__ g,
    const float* __restrict__ s,
    const float* __restrict__ gamma,
    const float* __restrict__ w_prev,
    const float* __restrict__ e,
    const float* __restrict__ a,
    float* __restrict__ out,
    float* s_sc, float* s_w, float* s_tmp, f32x4* s_red)
{
    const int t    = threadIdx.x;
    const int cg   = t & 15;
    const int rg   = t >> 4;
    const int wid  = t >> 6;
    const int lane = t & 63;
    const int coff = 4 * cg;

    const float* membn = memory + (size_t)(b + 1) * NN * MM;  // used only if PF
    float*       outb  = out    + (size_t)b * (NN + 1) * MM;

    // --- pass 1: cosine-sim scores from the register cache ---
    #pragma unroll
    for (int it = 0; it < ITS; ++it) {
        int n = it * 32 + rg;
        f32x4 m4 = mc[it];
        float ex = m4.x + 1e-16f, ey = m4.y + 1e-16f;
        float ez = m4.z + 1e-16f, ew = m4.w + 1e-16f;
        float d = ex * op.k4.x + ey * op.k4.y + ez * op.k4.z + ew * op.k4.w;
        float q = ex * ex + ey * ey + ez * ez + ew * ew;
        #pragma unroll
        for (int off = 8; off > 0; off >>= 1) {
            d += __shfl_xor(d, off, 64);
            q += __shfl_xor(q, off, 64);
        }
        if (cg == 0) s_sc[n] = op.bet * d / (fmaxf(sqrtf(q), 1e-8f) * op.kden);
    }
    lds_barrier();

    // issue next batch's small loads EARLY (before the pass-2 burst)
    Ops opn = op;
    if constexpr (PF)
        opn = load_ops(b + 1, coff, k, beta, g, s, gamma, w_prev, e, a);

    // --- softmax over N ---
    float sc0 = s_sc[t], sc1 = s_sc[t + 512];
    float mx = block_max(fmaxf(sc0, sc1), s_tmp);
    float e0 = __expf(sc0 - mx), e1 = __expf(sc1 - mx);
    float inv = 1.0f / block_sum(e0 + e1, s_tmp);

    // --- interpolate ---
    const float omg = 1.0f - op.gb;
    s_sc[t]       = op.gb * e0 * inv + omg * op.wp0;
    s_sc[t + 512] = op.gb * e1 * inv + omg * op.wp1;
    lds_barrier();

    // --- shift (3-tap circular) + sharpen ---
    float wv0, wv1;
    {
        int nm = (t == 0) ? NN - 1 : t - 1;
        wv0 = powf(op.s0 * s_sc[nm] + op.s1 * s_sc[t] + op.s2 * s_sc[t + 1], op.gam);
    }
    {
        int n = t + 512;
        int np = (n == NN - 1) ? 0 : n + 1;
        wv1 = powf(op.s0 * s_sc[n - 1] + op.s1 * s_sc[n] + op.s2 * s_sc[np], op.gam);
    }
    float winv = 1.0f / (block_sum(wv0 + wv1, s_tmp) + 1e-16f);
    s_w[t]       = wv0 * winv;
    s_w[t + 512] = wv1 * winv;
    lds_barrier();

    // --- pass 2: update from registers; stores interleaved 1:1 with
    //     next-batch prefetch loads; no barrier after this drains vmcnt,
    //     so the burst retires under reduce_read + next pass1 + middle ---
    f32x4 acc = {0.f, 0.f, 0.f, 0.f};
    #pragma unroll
    for (int it = 0; it < ITS; ++it) {
        int n = it * 32 + rg;
        f32x4 m4 = mc[it];
        float wn = s_w[n];
        acc.x += wn * m4.x; acc.y += wn * m4.y;
        acc.z += wn * m4.z; acc.w += wn * m4.w;
        f32x4 o;
        o.x = m4.x * (1.0f - wn * op.e4.x) + wn * op.a4.x;
        o.y = m4.y * (1.0f - wn * op.e4.y) + wn * op.a4.y;
        o.z = m4.z * (1.0f - wn * op.e4.z) + wn * op.a4.z;
        o.w = m4.w * (1.0f - wn * op.e4.w) + wn * op.a4.w;
        __builtin_nontemporal_store(o, (f32x4*)(outb + (size_t)(n + 1) * MM + coff));
        if constexpr (PF) {
            mc[it] = __builtin_nontemporal_load(
                (const f32x4*)(membn + (size_t)n * MM + coff));
        }
    }

    // --- reduce read accumulator; row 0 of outb = read ---
    #pragma unroll
    for (int off = 16; off <= 32; off <<= 1) {
        acc.x += __shfl_xor(acc.x, off, 64);
        acc.y += __shfl_xor(acc.y, off, 64);
        acc.z += __shfl_xor(acc.z, off, 64);
        acc.w += __shfl_xor(acc.w, off, 64);
    }
    if (lane < 16) s_red[wid * 16 + lane] = acc;
    lds_barrier();
    if (t < 16) {
        f32x4 r = {0.f, 0.f, 0.f, 0.f};
        #pragma unroll
        for (int wv = 0; wv < NW; ++wv) {
            f32x4 v = s_red[wv * 16 + t];
            r.x += v.x; r.y += v.y; r.z += v.z; r.w += v.w;
        }
        __builtin_nontemporal_store(r, (f32x4*)(outb + 4 * t));
    }
    lds_barrier();   // protect s_red reuse next batch
    return opn;
}

__global__ void __launch_bounds__(NT, 2) ntm_fused(
    const float* __restrict__ memory,
    const float* __restrict__ k,
    const float* __restrict__ beta,
    const float* __restrict__ g,
    const float* __restrict__ s,
    const float* __restrict__ gamma,
    const float* __restrict__ w_prev,
    const float* __restrict__ e,
    const float* __restrict__ a,
    float* __restrict__ out)
{
    __shared__ float  s_sc[NN];
    __shared__ float  s_w[NN];
    __shared__ float  s_tmp[NW];
    __shared__ f32x4  s_red[NW * 16];

    const int t    = threadIdx.x;
    const int cg   = t & 15;
    const int rg   = t >> 4;
    const int coff = 4 * cg;

    f32x4 mc[ITS];              // register cache: this thread's 512 B of the slice
    const int bbase = blockIdx.x * BPB;

    // small operands first (their consumption mustn't wait on the burst),
    // then the full first-batch load burst (max MLP)
    Ops op = load_ops(bbase, coff, k, beta, g, s, gamma, w_prev, e, a);
    {
        const float* memb = memory + (size_t)bbase * NN * MM;
        #pragma unroll
        for (int it = 0; it < ITS; ++it)
            mc[it] = __builtin_nontemporal_load(
                (const f32x4*)(memb + (size_t)(it * 32 + rg) * MM + coff));
    }

    for (int bi = 0; bi < BPB - 1; ++bi)
        op = process_batch<true>(bbase + bi, mc, op, memory, k, beta, g, s,
                                 gamma, w_prev, e, a, out,
                                 s_sc, s_w, s_tmp, s_red);
    process_batch<false>(bbase + BPB - 1, mc, op, memory, k, beta, g, s,
                         gamma, w_prev, e, a, out,
                         s_sc, s_w, s_tmp, s_red);
}

extern "C" void kernel_launch(void* const* d_in, const int* in_sizes, int n_in,
                              void* d_out, int out_size, void* d_ws, size_t ws_size,
                              hipStream_t stream) {
    ntm_fused<<<GRID, NT, 0, stream>>>(
        (const float*)d_in[0],  // memory (B,N,M)
        (const float*)d_in[1],  // k      (B,M)
        (const float*)d_in[2],  // beta   (B,1)
        (const float*)d_in[3],  // g      (B,1)
        (const float*)d_in[4],  // s      (B,3)
        (const float*)d_in[5],  // gamma  (B,1)
        (const float*)d_in[6],  // w_prev (B,N)
        (const float*)d_in[7],  // e      (B,M)
        (const float*)d_in[8],  // a      (B,M)
        (float*)d_out);
}